// Round 17
// baseline (726.838 us; speedup 1.0000x reference)
//
#include <hip/hip_runtime.h>
#include <hip/hip_bf16.h>

#define N_NODES 100000
#define N_EDGES 3200000
#define KITER   10
#define ALPHA   0.1f

#define SCAN_BS 512
#define SCAN_NB ((N_NODES + SCAN_BS - 1) / SCAN_BS)   // 196

#define NSUB    256         // segments per bucket
#define SEGCAP  2048        // per-segment capacity (mean ~1562, +12σ)
#define OVCAP   262144      // overflow capacity (normally 0 used)
#define CB_EDGES 1024       // edges per convert block
#define CB_CAP   256        // per-bucket LDS capacity (mean 128, +12σ)
#define NWIN    128         // node windows per bucket (98 nodes each)
#define WN      98          // nodes per window
#define SB_CAP  48          // per-window LDS bin cap in subpart (mean 12, +10σ)
#define SUBCAP  4096        // per-window sub-bucket capacity (mean 3136, +17σ)

typedef __attribute__((ext_vector_type(4))) float f32x4;
typedef __attribute__((ext_vector_type(8))) short bf16x8;
typedef __attribute__((ext_vector_type(4))) unsigned int u32x4;
typedef unsigned short u16;
typedef unsigned int u32;

#define WAITV(N) asm volatile("s_waitcnt vmcnt(" #N ")" ::: "memory")
#define WAITL0   asm volatile("s_waitcnt lgkmcnt(0)" ::: "memory")
#define MEMFENCE asm volatile("" ::: "memory")

__device__ inline float bf2f(u16 u) {
    unsigned int x = ((unsigned int)u) << 16;
    return __uint_as_float(x);
}
__device__ inline float bf2f_lo(unsigned int w) { return __uint_as_float(w << 16); }
__device__ inline float bf2f_hi(unsigned int w) { return __uint_as_float(w & 0xffff0000u); }
__device__ inline u16 f2bf(float f) {
    __hip_bfloat16 h = __float2bfloat16(f);
    return *reinterpret_cast<u16*>(&h);
}
__device__ inline bf16x8 cvt8(float4 lo, float4 hi) {
    bf16x8 r;
    r[0] = (short)f2bf(lo.x); r[1] = (short)f2bf(lo.y);
    r[2] = (short)f2bf(lo.z); r[3] = (short)f2bf(lo.w);
    r[4] = (short)f2bf(hi.x); r[5] = (short)f2bf(hi.y);
    r[6] = (short)f2bf(hi.z); r[7] = (short)f2bf(hi.w);
    return r;
}
// async global(16B/lane) -> LDS (wave-uniform base + lane*16)
__device__ inline void glds16(const u16* g, u16* l) {
    __builtin_amdgcn_global_load_lds(
        (const __attribute__((address_space(1))) u32*)g,
        (__attribute__((address_space(3))) u32*)l, 16, 0, 0);
}

// edge_index may arrive as int64 (reference dtype) or int32 (harness policy).
__global__ void k_detect(const unsigned int* e32, int* flag) {
    if (threadIdx.x == 0) {
        int is64 = 1;
        for (int i = 0; i < 64; ++i)
            if (e32[2 * i + 1] != 0u) { is64 = 0; break; }
        *flag = is64;
    }
}

__device__ inline int eidx(const void* p, int is64, int i) {
    if (is64) return (int)((const long long*)p)[i];
    return ((const int*)p)[i];
}

// Convert v3: LDS-staged coarse bucketing (8 buckets), no per-edge atomics.
__global__ __launch_bounds__(256) void k_convert_bucket3(
    const void* edges, const int* flag,
    unsigned int* __restrict__ buckets, int* __restrict__ bcur,
    int2* __restrict__ ovf, int* __restrict__ ovfn) {
    __shared__ unsigned int lbuf[8][CB_CAP];   // 8 KB
    __shared__ int lcnt[8];
    __shared__ int lbase[8];
    int t = threadIdx.x;
    if (t < 8) lcnt[t] = 0;
    __syncthreads();
    int e0 = blockIdx.x * CB_EDGES;
    int is64 = *flag;
#pragma unroll
    for (int j = 0; j < CB_EDGES / 256; ++j) {
        int i = e0 + j * 256 + t;              // coalesced per j-step
        int r = eidx(edges, is64, i);
        int c = eidx(edges, is64, N_EDGES + i);
        int b = c / 12500;
        int coff = c - b * 12500;
        unsigned int pack = ((unsigned)coff << 17) | (unsigned)r;
        int pos = atomicAdd(&lcnt[b], 1);
        if (pos < CB_CAP) {
            lbuf[b][pos] = pack;
        } else {
            int op = atomicAdd(ovfn, 1);
            if (op < OVCAP) ovf[op] = make_int2(c, r);
        }
    }
    __syncthreads();
    int sub = blockIdx.x & (NSUB - 1);
    if (t < 8) {
        int n = min(lcnt[t], CB_CAP);
        lbase[t] = atomicAdd(&bcur[t * NSUB + sub], n);
    }
    __syncthreads();
#pragma unroll
    for (int bb = 0; bb < 8; ++bb) {
        int n = min(lcnt[bb], CB_CAP);
        int base = lbase[bb];
        size_t segoff = ((size_t)(bb * NSUB + sub)) * SEGCAP;
        for (int i = t; i < n; i += 256) {
            int pos = base + i;
            unsigned int pk = lbuf[bb][i];
            if (pos < SEGCAP) {
                buckets[segoff + pos] = pk;
            } else {
                int c = bb * 12500 + (int)(pk >> 17);
                int r = (int)(pk & 0x1FFFFu);
                int op = atomicAdd(ovfn, 1);
                if (op < OVCAP) ovf[op] = make_int2(c, r);
            }
        }
    }
}

// Sub-partition: segment (b,sub) -> 128 node-window sub-buckets (WN=98 nodes).
__global__ __launch_bounds__(256) void k_subpart(
    const unsigned int* __restrict__ buckets, const int* __restrict__ bcur,
    unsigned int* __restrict__ subbuck, int* __restrict__ scur,
    int2* __restrict__ ovf, int* __restrict__ ovfn) {
    __shared__ unsigned int sbin[NWIN][SB_CAP];   // 24.6 KB
    __shared__ int scnt[NWIN];
    __shared__ int sbase[NWIN];
    int t = threadIdx.x;
    int b = blockIdx.x & 7;
    int sub = blockIdx.x >> 3;
    int idx = b * NSUB + sub;
    if (t < NWIN) scnt[t] = 0;
    __syncthreads();
    int n = min(bcur[idx], SEGCAP);
    const unsigned int* bk = buckets + (size_t)idx * SEGCAP;
    for (int e = t; e < n; e += 256) {
        unsigned int pk = bk[e];
        int j = (int)(pk >> 17) / WN;             // window 0..127
        int p = atomicAdd(&scnt[j], 1);
        if (p < SB_CAP) {
            sbin[j][p] = pk;
        } else {
            int c = b * 12500 + (int)(pk >> 17);
            int r = (int)(pk & 0x1FFFFu);
            int op = atomicAdd(ovfn, 1);
            if (op < OVCAP) ovf[op] = make_int2(c, r);
        }
    }
    __syncthreads();
    if (t < NWIN) {
        int cnt = min(scnt[t], SB_CAP);
        sbase[t] = atomicAdd(&scur[b * NWIN + t], cnt);
    }
    __syncthreads();
    for (int i = t; i < NWIN * SB_CAP; i += 256) {
        int j = i / SB_CAP, s = i % SB_CAP;
        if (s < min(scnt[j], SB_CAP)) {
            int pos = sbase[j] + s;
            unsigned int pk = sbin[j][s];
            if (pos < SUBCAP) {
                subbuck[((size_t)(b * NWIN + j)) * SUBCAP + pos] = pk;
            } else {
                int c = b * 12500 + (int)(pk >> 17);
                int r = (int)(pk & 0x1FFFFu);
                int op = atomicAdd(ovfn, 1);
                if (op < OVCAP) ovf[op] = make_int2(c, r);
            }
        }
    }
}

// Degree histogram v2: one block per node-window (1024 blocks).
__global__ __launch_bounds__(256) void k_deghist2(const unsigned int* __restrict__ subbuck,
                                                  const int* __restrict__ scur,
                                                  int* __restrict__ deg) {
    __shared__ int h[WN];
    int t = threadIdx.x;
    int b = blockIdx.x & 7;
    int j = blockIdx.x >> 3;                  // 0..NWIN-1
    int base_node = b * 12500 + j * WN;
    int nn = min(WN, 12500 - j * WN);
    if (t < WN) h[t] = 0;
    __syncthreads();
    int idx = b * NWIN + j;
    int n = min(scur[idx], SUBCAP);
    const unsigned int* sb = subbuck + (size_t)idx * SUBCAP;
    for (int e = t; e < n; e += 256)
        atomicAdd(&h[(int)(sb[e] >> 17) - j * WN], 1);
    __syncthreads();
    if (t < nn) deg[base_node + t] = h[t];    // plain store (exclusive window)
}

// Overflow deg contribution (normally zero entries) — runs AFTER k_deghist2
__global__ void k_deg_ovf(const int2* __restrict__ ovf, const int* __restrict__ ovfn,
                          int* deg) {
    int n = min(*ovfn, OVCAP);
    for (int i = blockIdx.x * 256 + threadIdx.x; i < n; i += gridDim.x * 256)
        atomicAdd(&deg[ovf[i].x], 1);
}

// ---- two-level scan: local scan -> scan of block sums -> apply ----
__global__ __launch_bounds__(SCAN_BS) void k_scan_part(const int* __restrict__ deg,
                                                       int* __restrict__ ptr,
                                                       int* __restrict__ bsum) {
    __shared__ int lds[SCAN_BS];
    int t = threadIdx.x;
    int idx = blockIdx.x * SCAN_BS + t;
    int s = (idx < N_NODES) ? deg[idx] : 0;
    lds[t] = s;
    __syncthreads();
#pragma unroll
    for (int off = 1; off < SCAN_BS; off <<= 1) {
        int v = (t >= off) ? lds[t - off] : 0;
        __syncthreads();
        lds[t] += v;
        __syncthreads();
    }
    if (idx < N_NODES) ptr[idx] = lds[t] - s;     // exclusive local
    if (t == SCAN_BS - 1) bsum[blockIdx.x] = lds[t];
}

__global__ __launch_bounds__(256) void k_scan_bsum(const int* __restrict__ bsum,
                                                   int* __restrict__ boff,
                                                   int* __restrict__ ptr) {
    __shared__ int lds[256];
    int t = threadIdx.x;
    int s = (t < SCAN_NB) ? bsum[t] : 0;
    lds[t] = s;
    __syncthreads();
#pragma unroll
    for (int off = 1; off < 256; off <<= 1) {
        int v = (t >= off) ? lds[t - off] : 0;
        __syncthreads();
        lds[t] += v;
        __syncthreads();
    }
    if (t < SCAN_NB) boff[t] = lds[t] - s;        // exclusive
    if (t == 255) ptr[N_NODES] = lds[t];          // total (== N_EDGES)
}

__global__ __launch_bounds__(SCAN_BS) void k_scan_apply(const int* __restrict__ deg,
                                                        const int* __restrict__ boff,
                                                        int* __restrict__ ptr,
                                                        int* __restrict__ cursor,
                                                        float* __restrict__ dinv) {
    int idx = blockIdx.x * SCAN_BS + threadIdx.x;
    if (idx >= N_NODES) return;
    int p = ptr[idx] + boff[blockIdx.x];
    ptr[idx] = p;
    cursor[idx] = p;
    dinv[idx] = rsqrtf((float)(deg[idx] + 1));    // +1 self loop
}

// Fill v6: one block EXCLUSIVELY owns node window (b,j) -> cursors in LDS.
__global__ __launch_bounds__(256) void k_fill6(const unsigned int* __restrict__ subbuck,
                                               const int* __restrict__ scur,
                                               const int* __restrict__ ptr,
                                               int* __restrict__ cursor,
                                               int* __restrict__ csr_src) {
    __shared__ int lcur[WN];
    int t = threadIdx.x;
    int b = blockIdx.x & 7;
    int j = blockIdx.x >> 3;                  // 0..NWIN-1
    int base_node = b * 12500 + j * WN;
    int nn = min(WN, 12500 - j * WN);         // last window is short
    if (t < nn) lcur[t] = ptr[base_node + t];
    __syncthreads();
    int idx = b * NWIN + j;
    int n = min(scur[idx], SUBCAP);
    const unsigned int* sb = subbuck + (size_t)idx * SUBCAP;
    for (int e = t; e < n; e += 256) {
        unsigned int pk = sb[e];
        int local = (int)(pk >> 17) - j * WN; // in [0, nn)
        int r = (int)(pk & 0x1FFFFu);
        int pos = atomicAdd(&lcur[local], 1); // LDS atomic — cheap
        csr_src[pos] = r;
    }
    __syncthreads();
    if (t < nn) cursor[base_node + t] = lcur[t];
}

// Overflow cleanup (normally zero entries) — runs AFTER k_fill6
__global__ void k_fill_ovf(const int2* __restrict__ ovf, const int* __restrict__ ovfn,
                           int* cursor, int* __restrict__ csr_src) {
    int n = min(*ovfn, OVCAP);
    for (int i = blockIdx.x * 256 + threadIdx.x; i < n; i += gridDim.x * 256) {
        int2 e = ovf[i];
        csr_src[atomicAdd(&cursor[e.x], 1)] = e.y;
    }
}

// W1 [500,256] f32 -> W1s bf16 [ks=16][n=256][kk=32] with slot-XOR swizzle.
__global__ void k_wconv1(const float* W1, u16* W1s) {
    int idx = blockIdx.x * 256 + threadIdx.x;
    if (idx >= 16 * 256 * 32) return;
    int ks = idx / (256 * 32);
    int rem = idx % (256 * 32);
    int n = rem / 32, kk = rem % 32;
    int k = ks * 32 + kk;
    float v = (k < 500) ? W1[k * 256 + n] : 0.0f;
    int slot = kk >> 3, kl = kk & 7;
    int sslot = slot ^ ((n >> 1) & 3);
    W1s[ks * 8192 + n * 32 + sslot * 8 + kl] = f2bf(v);
}

// W2 [256,64] f32 -> W2s bf16 swizzled [ks=8][n=64][kk=32] (unswizzled slots)
__global__ void k_wconv2(const float* W2, u16* W2s) {
    int idx = blockIdx.x * 256 + threadIdx.x;
    if (idx >= 8 * 64 * 32) return;
    int ks = idx / (64 * 32);
    int rem = idx % (64 * 32);
    int n = rem / 32, kk = rem % 32;
    int k = ks * 32 + kk;
    W2s[idx] = f2bf(W2[k * 64 + n]);
}

// Fused MLP v6: 128x256 tile, 8 waves, BK=32, 16 steps. T3/T4-lite K-loop:
// TRIPLE-buffered LDS, loads issued 2 steps ahead, raw s_barrier + counted
// vmcnt (never 0 in steady state) so prefetches stay in flight across
// barriers. Per step issues exactly 4 vmem ops (2 x-loads + 2 glds):
//   top wait  vmcnt(8): glds(ks) done   (2 steps of cover)
//   end wait  vmcnt(6): x(ks+1) done    (2 steps of cover)
// Tail steps use exact reduced counts. lgkmcnt(0) before each barrier
// retires ds_writes AND stragglers' ds_reads (buffer-reuse safety: each
// buffer is rewritten >=2 barriers after its last read).
#define MLP2_ROWS 128
#define HSTR 264    // u16 stride for H rows
#define H2STR 72    // u16 stride for pack buffer

__global__ __launch_bounds__(512, 4) void k_mlp2(
    const float* __restrict__ x, const u16* __restrict__ W1s,
    const float* __restrict__ b1, const u16* __restrict__ W2s,
    const float* __restrict__ b2, const float* __restrict__ dinv,
    u16* __restrict__ h_bf, u16* __restrict__ zs0) {

    __shared__ u16 smem[36864];   // 73728 B: [A 3x4096 | B 3x8192]; H reuses
    u16* Abuf = smem;             // 3 * 4096 u16
    u16* Bbuf = smem + 12288;     // 3 * 8192 u16

    int t = threadIdx.x;
    int lane = t & 63, w = t >> 6;
    int wr = w >> 2, wc = w & 3;
    int cl = lane & 15, hi = lane >> 4;
    int m0 = blockIdx.x * MLP2_ROWS;

    // A staging coords: thread t stages row sr, k-slot skq (8 k's)
    int sr = t >> 2, skq = t & 3;
    int srow = min(m0 + sr, N_NODES - 1);
    const size_t XMAX = (size_t)N_NODES * 500 - 4;  // last valid float4 start
    size_t sbase = (size_t)srow * 500 + skq * 8;
    int sAoff = sr * 32 + ((skq ^ ((sr >> 1) & 3)) << 3);  // swizzled u16 offset

    f32x4 acc[4][4];
    f32x4 zero = {0.f, 0.f, 0.f, 0.f};
#pragma unroll
    for (int nt = 0; nt < 4; ++nt)
#pragma unroll
        for (int i = 0; i < 4; ++i) acc[nt][i] = zero;

    float4 xs[2][2];

    // ---- prologue: issue x0,g0,x1,g1; write A0; barrier ----
    {
        size_t f0 = sbase;
        size_t a0 = f0 > XMAX ? XMAX : f0;
        size_t a1 = (f0 + 4) > XMAX ? XMAX : (f0 + 4);
        float4 p0 = *(const float4*)(x + a0);
        float4 p1 = *(const float4*)(x + a1);
        MEMFENCE;
        glds16(W1s + (w * 2 + 0) * 512 + lane * 8, Bbuf + (w * 2 + 0) * 512);
        glds16(W1s + (w * 2 + 1) * 512 + lane * 8, Bbuf + (w * 2 + 1) * 512);
        MEMFENCE;
        size_t f1 = sbase + 32;
        size_t b0 = f1 > XMAX ? XMAX : f1;
        size_t b1a = (f1 + 4) > XMAX ? XMAX : (f1 + 4);
        xs[1][0] = *(const float4*)(x + b0);
        xs[1][1] = *(const float4*)(x + b1a);
        MEMFENCE;
        const u16* bs1 = W1s + 8192;
        glds16(bs1 + (w * 2 + 0) * 512 + lane * 8, Bbuf + 8192 + (w * 2 + 0) * 512);
        glds16(bs1 + (w * 2 + 1) * 512 + lane * 8, Bbuf + 8192 + (w * 2 + 1) * 512);
        WAITV(6);                        // x0 done (6 ops issued after it)
        __builtin_amdgcn_sched_barrier(0);
        bf16x8 av = cvt8(p0, p1);
        *(bf16x8*)&Abuf[sAoff] = av;     // A0 -> buf0
        WAITL0;
        __builtin_amdgcn_s_barrier();
    }

#pragma unroll
    for (int ks = 0; ks < 16; ++ks) {
        const int b_cur = ks % 3, b_wr = (ks + 1) % 3, b_pf = (ks + 2) % 3;
        if (ks + 2 <= 15) {
            // issue x(ks+2) -> xs[ks&1], glds(ks+2) -> Bbuf[b_pf]
            size_t f = sbase + (size_t)(ks + 2) * 32;
            size_t a0 = f > XMAX ? XMAX : f;
            size_t a1 = (f + 4) > XMAX ? XMAX : (f + 4);
            xs[ks & 1][0] = *(const float4*)(x + a0);
            xs[ks & 1][1] = *(const float4*)(x + a1);
            MEMFENCE;
            const u16* bsrc = W1s + (ks + 2) * 8192;
            glds16(bsrc + (w * 2 + 0) * 512 + lane * 8,
                   Bbuf + b_pf * 8192 + (w * 2 + 0) * 512);
            glds16(bsrc + (w * 2 + 1) * 512 + lane * 8,
                   Bbuf + b_pf * 8192 + (w * 2 + 1) * 512);
            MEMFENCE;
        }
        // top wait: glds(ks) complete (counted, prefetches stay in flight)
        if (ks <= 13)      { WAITV(8); }
        else if (ks == 14) { WAITV(4); }
        else               { WAITV(0); }
        __builtin_amdgcn_sched_barrier(0);
        // ---- compute on b_cur: pure ds_read + MFMA ----
        const u16* Ab = Abuf + b_cur * 4096;
        const u16* Bb = Bbuf + b_cur * 8192;
        bf16x8 af[4];
#pragma unroll
        for (int i = 0; i < 4; ++i) {
            int row = wr * 64 + i * 16 + cl;
            af[i] = *(const bf16x8*)&Ab[row * 32 + ((hi ^ ((row >> 1) & 3)) << 3)];
        }
#pragma unroll
        for (int nt = 0; nt < 4; ++nt) {
            int n = wc * 64 + nt * 16 + cl;
            bf16x8 bv = *(const bf16x8*)&Bb[n * 32 + ((hi ^ ((n >> 1) & 3)) << 3)];
#pragma unroll
            for (int i = 0; i < 4; ++i)
                acc[nt][i] = __builtin_amdgcn_mfma_f32_16x16x32_bf16(af[i], bv, acc[nt][i], 0, 0, 0);
        }
        if (ks <= 14) {
            // end wait: x(ks+1) done; cvt + ds_write A(ks+1) -> buf[b_wr]
            if (ks <= 13) { WAITV(6); } else { WAITV(2); }
            __builtin_amdgcn_sched_barrier(0);
            bf16x8 av = cvt8(xs[(ks + 1) & 1][0], xs[(ks + 1) & 1][1]);
            *(bf16x8*)&Abuf[b_wr * 4096 + sAoff] = av;
        }
        WAITL0;
        __builtin_amdgcn_s_barrier();
    }

    // ---- epilogue 1: +b1, relu -> H (smem reused; K-loop bufs dead) ----
    u16* H = smem;
#pragma unroll
    for (int nt = 0; nt < 4; ++nt) {
        int col = wc * 64 + nt * 16 + cl;
        float bb = b1[col];
#pragma unroll
        for (int i = 0; i < 4; ++i) {
            int row = wr * 64 + i * 16 + hi * 4;
#pragma unroll
            for (int r = 0; r < 4; ++r)
                H[(row + r) * HSTR + col] = f2bf(fmaxf(acc[nt][i][r] + bb, 0.0f));
        }
    }
    __syncthreads();

    // ---- GEMM2: wave w handles rows w*16..+15; W2s direct from global ----
    f32x4 acc2[4];
#pragma unroll
    for (int i = 0; i < 4; ++i) acc2[i] = zero;
    int rA0 = w * 16 + cl;
#pragma unroll
    for (int ks2 = 0; ks2 < 8; ++ks2) {
        bf16x8 afv = *(const bf16x8*)&H[rA0 * HSTR + ks2 * 32 + 8 * hi];
#pragma unroll
        for (int nt = 0; nt < 4; ++nt) {
            bf16x8 bv = *(const bf16x8*)(W2s + (ks2 * 64 + nt * 16 + cl) * 32 + 8 * hi);
            acc2[nt] = __builtin_amdgcn_mfma_f32_16x16x32_bf16(afv, bv, acc2[nt], 0, 0, 0);
        }
    }
    __syncthreads();   // H dead; reuse as pack buffer

    // ---- epilogue 2: +b2 -> H2 ----
    u16* H2 = smem;
    {
        int rl0 = w * 16 + hi * 4;
#pragma unroll
        for (int nt = 0; nt < 4; ++nt) {
            int col = nt * 16 + cl;
            float bb = b2[col];
#pragma unroll
            for (int r = 0; r < 4; ++r)
                H2[(rl0 + r) * H2STR + col] = f2bf(acc2[nt][r] + bb);
        }
    }
    __syncthreads();

    // ---- pack & store: thread t handles a quarter row (16 u16 = 32B) ----
    {
        int rl = t >> 2, q = t & 3;
        int grow = m0 + rl;
        if (grow < N_NODES) {
            float dv = dinv[grow];
            const u32x4* src = (const u32x4*)&H2[rl * H2STR + q * 16];
            u32x4 hq[2] = {src[0], src[1]};
            u32x4 zq[2];
#pragma unroll
            for (int i = 0; i < 2; ++i) {
#pragma unroll
                for (int jj = 0; jj < 4; ++jj) {
                    unsigned int hw = hq[i][jj];
                    float lo = dv * bf2f_lo(hw);
                    float hi2 = dv * bf2f_hi(hw);
                    zq[i][jj] = (unsigned)f2bf(lo) | ((unsigned)f2bf(hi2) << 16);
                }
            }
            u32x4* hd = (u32x4*)(h_bf + (size_t)grow * 64 + q * 16);
            u32x4* zd = (u32x4*)(zs0 + (size_t)grow * 64 + q * 16);
            hd[0] = hq[0]; hd[1] = hq[1];
            zd[0] = zq[0]; zd[1] = zq[1];
        }
    }
}

// Propagation v3: one wave per node, dwordx4 gathers of 8 edges.
__global__ __launch_bounds__(256) void k_prop3(
    const u16* __restrict__ zs_in, const u16* __restrict__ h_bf,
    const float* __restrict__ dinv, const int* __restrict__ ptr,
    const int* __restrict__ csr_src, u16* __restrict__ zs_out,
    float* __restrict__ out, int last) {

    int lane = threadIdx.x & 63;
    int g = lane >> 3;   // edge slot 0..7
    int c = lane & 7;    // channels 8c..8c+7
    int v = blockIdx.x * 4 + (threadIdx.x >> 6);
    if (v >= N_NODES) return;
    int s0 = ptr[v], s1 = ptr[v + 1];

    float a0 = 0.f, a1 = 0.f, a2 = 0.f, a3 = 0.f;
    float a4 = 0.f, a5 = 0.f, a6 = 0.f, a7 = 0.f;
    float b0 = 0.f, b1 = 0.f, b2 = 0.f, b3 = 0.f;
    float b4 = 0.f, b5 = 0.f, b6 = 0.f, b7 = 0.f;

    for (int base = s0; base < s1; base += 64) {
        int nwin = min(64, s1 - base);
        int ei = base + lane;
        int sv = (ei < s1) ? csr_src[ei] : v;   // fallback: safe address
        int j = 0;
        for (; j + 16 <= nwin; j += 16) {
            int u0 = __shfl(sv, j + g, 64);
            int u1 = __shfl(sv, j + 8 + g, 64);
            u32x4 q0 = *(const u32x4*)(zs_in + (size_t)u0 * 64 + c * 8);
            u32x4 q1 = *(const u32x4*)(zs_in + (size_t)u1 * 64 + c * 8);
            a0 += bf2f_lo(q0.x); a1 += bf2f_hi(q0.x);
            a2 += bf2f_lo(q0.y); a3 += bf2f_hi(q0.y);
            a4 += bf2f_lo(q0.z); a5 += bf2f_hi(q0.z);
            a6 += bf2f_lo(q0.w); a7 += bf2f_hi(q0.w);
            b0 += bf2f_lo(q1.x); b1 += bf2f_hi(q1.x);
            b2 += bf2f_lo(q1.y); b3 += bf2f_hi(q1.y);
            b4 += bf2f_lo(q1.z); b5 += bf2f_hi(q1.z);
            b6 += bf2f_lo(q1.w); b7 += bf2f_hi(q1.w);
        }
        for (; j < nwin; j += 8) {
            int idx = j + g;
            int u = __shfl(sv, idx, 64);  // idx<=63; invalid lanes hold v (safe)
            u32x4 q = *(const u32x4*)(zs_in + (size_t)u * 64 + c * 8);
            if (idx < nwin) {
                a0 += bf2f_lo(q.x); a1 += bf2f_hi(q.x);
                a2 += bf2f_lo(q.y); a3 += bf2f_hi(q.y);
                a4 += bf2f_lo(q.z); a5 += bf2f_hi(q.z);
                a6 += bf2f_lo(q.w); a7 += bf2f_hi(q.w);
            }
        }
    }
    a0 += b0; a1 += b1; a2 += b2; a3 += b3;
    a4 += b4; a5 += b5; a6 += b6; a7 += b7;
#pragma unroll
    for (int off = 8; off <= 32; off <<= 1) {
        a0 += __shfl_xor(a0, off, 64); a1 += __shfl_xor(a1, off, 64);
        a2 += __shfl_xor(a2, off, 64); a3 += __shfl_xor(a3, off, 64);
        a4 += __shfl_xor(a4, off, 64); a5 += __shfl_xor(a5, off, 64);
        a6 += __shfl_xor(a6, off, 64); a7 += __shfl_xor(a7, off, 64);
    }

    float dv = dinv[v];
    u32x4 qs = *(const u32x4*)(zs_in + (size_t)v * 64 + c * 8);
    u32x4 qh = *(const u32x4*)(h_bf + (size_t)v * 64 + c * 8);
    float z0 = (1.0f - ALPHA) * dv * (a0 + bf2f_lo(qs.x)) + ALPHA * bf2f_lo(qh.x);
    float z1 = (1.0f - ALPHA) * dv * (a1 + bf2f_hi(qs.x)) + ALPHA * bf2f_hi(qh.x);
    float z2 = (1.0f - ALPHA) * dv * (a2 + bf2f_lo(qs.y)) + ALPHA * bf2f_lo(qh.y);
    float z3 = (1.0f - ALPHA) * dv * (a3 + bf2f_hi(qs.y)) + ALPHA * bf2f_hi(qh.y);
    float z4 = (1.0f - ALPHA) * dv * (a4 + bf2f_lo(qs.z)) + ALPHA * bf2f_lo(qh.z);
    float z5 = (1.0f - ALPHA) * dv * (a5 + bf2f_hi(qs.z)) + ALPHA * bf2f_hi(qh.z);
    float z6 = (1.0f - ALPHA) * dv * (a6 + bf2f_lo(qs.w)) + ALPHA * bf2f_lo(qh.w);
    float z7 = (1.0f - ALPHA) * dv * (a7 + bf2f_hi(qs.w)) + ALPHA * bf2f_hi(qh.w);

    if (!last) {
        if (g == 0) {
            u32x4 o;
            o.x = (unsigned)f2bf(dv * z0) | ((unsigned)f2bf(dv * z1) << 16);
            o.y = (unsigned)f2bf(dv * z2) | ((unsigned)f2bf(dv * z3) << 16);
            o.z = (unsigned)f2bf(dv * z4) | ((unsigned)f2bf(dv * z5) << 16);
            o.w = (unsigned)f2bf(dv * z6) | ((unsigned)f2bf(dv * z7) << 16);
            *(u32x4*)(zs_out + (size_t)v * 64 + c * 8) = o;
        }
    } else {
        float m = fmaxf(fmaxf(fmaxf(z0, z1), fmaxf(z2, z3)),
                        fmaxf(fmaxf(z4, z5), fmaxf(z6, z7)));
#pragma unroll
        for (int off = 1; off <= 4; off <<= 1) m = fmaxf(m, __shfl_xor(m, off, 64));
        float p = expf(z0 - m) + expf(z1 - m) + expf(z2 - m) + expf(z3 - m)
                + expf(z4 - m) + expf(z5 - m) + expf(z6 - m) + expf(z7 - m);
#pragma unroll
        for (int off = 1; off <= 4; off <<= 1) p += __shfl_xor(p, off, 64);
        float ls = logf(p);
        if (g == 0) {
            f32x4 o1 = {z0 - m - ls, z1 - m - ls, z2 - m - ls, z3 - m - ls};
            f32x4 o2 = {z4 - m - ls, z5 - m - ls, z6 - m - ls, z7 - m - ls};
            *(f32x4*)(out + (size_t)v * 64 + c * 8) = o1;
            *(f32x4*)(out + (size_t)v * 64 + c * 8 + 4) = o2;
        }
    }
}

extern "C" void kernel_launch(void* const* d_in, const int* in_sizes, int n_in,
                              void* d_out, int out_size, void* d_ws, size_t ws_size,
                              hipStream_t stream) {
    const float* x  = (const float*)d_in[0];
    const void* edges = d_in[1];
    const float* W1 = (const float*)d_in[2];
    const float* b1 = (const float*)d_in[3];
    const float* W2 = (const float*)d_in[4];
    const float* b2 = (const float*)d_in[5];
    float* out = (float*)d_out;

    char* ws = (char*)d_ws;
    size_t off = 0;
    auto alloc = [&](size_t bytes) -> void* {
        void* p = ws + off;
        off = (off + bytes + 255) & ~(size_t)255;
        return p;
    };
    int*   flag    = (int*)alloc(4);
    int*   deg     = (int*)alloc((size_t)N_NODES * 4);
    float* dinv    = (float*)alloc((size_t)N_NODES * 4);
    int*   ptr     = (int*)alloc((size_t)(N_NODES + 1) * 4);
    int*   cursor  = (int*)alloc((size_t)N_NODES * 4);
    int*   bsum    = (int*)alloc((size_t)SCAN_NB * 4);
    int*   boff    = (int*)alloc((size_t)SCAN_NB * 4);
    int*   csr_src = (int*)alloc((size_t)N_EDGES * 4);
    u16*   W1s     = (u16*)alloc((size_t)16 * 256 * 32 * 2);
    u16*   W2s     = (u16*)alloc((size_t)8 * 64 * 32 * 2);
    u16*   h_bf    = (u16*)alloc((size_t)N_NODES * 64 * 2);
    u16*   zsA     = (u16*)alloc((size_t)N_NODES * 64 * 2);
    u32*   buckets = (u32*)alloc((size_t)8 * NSUB * SEGCAP * 4);   // 16.8MB
    u32*   subbuck = (u32*)alloc((size_t)8 * NWIN * SUBCAP * 4);   // 16.8MB; zsB aliases
    int*   bctl    = (int*)alloc((size_t)(8 * NSUB + 8 * NWIN + 16) * 4);
    int2*  ovf     = (int2*)alloc((size_t)OVCAP * 8);
    u16*   zsB     = (u16*)subbuck;  // subbuck dead after fill6; 16.8MB >= 12.8MB

    int* bcur = bctl;                      // [8*NSUB]
    int* scur = bctl + 8 * NSUB;           // [8*NWIN]
    int* ovfn = bctl + 8 * NSUB + 8 * NWIN;

    hipMemsetAsync(deg, 0, (size_t)N_NODES * 4, stream);
    hipMemsetAsync(bctl, 0, (size_t)(8 * NSUB + 8 * NWIN + 16) * 4, stream);
    k_detect<<<1, 64, 0, stream>>>((const unsigned int*)edges, flag);
    k_convert_bucket3<<<N_EDGES / CB_EDGES, 256, 0, stream>>>(edges, flag,
                                                              buckets, bcur, ovf, ovfn);
    k_subpart<<<8 * NSUB, 256, 0, stream>>>(buckets, bcur, subbuck, scur, ovf, ovfn);
    k_deghist2<<<8 * NWIN, 256, 0, stream>>>(subbuck, scur, deg);
    k_deg_ovf<<<32, 256, 0, stream>>>(ovf, ovfn, deg);
    k_scan_part<<<SCAN_NB, SCAN_BS, 0, stream>>>(deg, ptr, bsum);
    k_scan_bsum<<<1, 256, 0, stream>>>(bsum, boff, ptr);
    k_scan_apply<<<SCAN_NB, SCAN_BS, 0, stream>>>(deg, boff, ptr, cursor, dinv);
    k_fill6<<<8 * NWIN, 256, 0, stream>>>(subbuck, scur, ptr, cursor, csr_src);
    k_fill_ovf<<<64, 256, 0, stream>>>(ovf, ovfn, cursor, csr_src);
    k_wconv1<<<(16 * 256 * 32 + 255) / 256, 256, 0, stream>>>(W1, W1s);
    k_wconv2<<<(8 * 64 * 32 + 255) / 256, 256, 0, stream>>>(W2, W2s);
    k_mlp2<<<(N_NODES + MLP2_ROWS - 1) / MLP2_ROWS, 512, 0, stream>>>(x, W1s, b1, W2s, b2,
                                                                      dinv, h_bf, zsA);

    const u16* zin = zsA;
    u16* zout = zsB;
    for (int k = 0; k < KITER; ++k) {
        int last = (k == KITER - 1) ? 1 : 0;
        k_prop3<<<(N_NODES + 3) / 4, 256, 0, stream>>>(zin, h_bf, dinv, ptr, csr_src,
                                                       zout, out, last);
        u16* t = zout;
        zout = (u16*)zin;
        zin = t;
    }
}

// Round 18
// 705.097 us; speedup vs baseline: 1.0308x; 1.0308x over previous
//
#include <hip/hip_runtime.h>
#include <hip/hip_bf16.h>

#define N_NODES 100000
#define N_EDGES 3200000
#define KITER   10
#define ALPHA   0.1f

#define SCAN_BS 512
#define SCAN_NB ((N_NODES + SCAN_BS - 1) / SCAN_BS)   // 196

#define NSUB    256         // segments per bucket
#define SEGCAP  2048        // per-segment capacity (mean ~1562, +12σ)
#define OVCAP   262144      // overflow capacity (normally 0 used)
#define CB_EDGES 1024       // edges per convert block
#define CB_CAP   256        // per-bucket LDS capacity (mean 128, +12σ)
#define NWIN    128         // node windows per bucket (98 nodes each)
#define WN      98          // nodes per window
#define SB_CAP  48          // per-window LDS bin cap in subpart (mean 12, +10σ)
#define SUBCAP  4096        // per-window sub-bucket capacity (mean 3136, +17σ)

typedef __attribute__((ext_vector_type(4))) float f32x4;
typedef __attribute__((ext_vector_type(8))) short bf16x8;
typedef __attribute__((ext_vector_type(4))) unsigned int u32x4;
typedef unsigned short u16;
typedef unsigned int u32;

__device__ inline float bf2f(u16 u) {
    unsigned int x = ((unsigned int)u) << 16;
    return __uint_as_float(x);
}
__device__ inline float bf2f_lo(unsigned int w) { return __uint_as_float(w << 16); }
__device__ inline float bf2f_hi(unsigned int w) { return __uint_as_float(w & 0xffff0000u); }
__device__ inline u16 f2bf(float f) {
    __hip_bfloat16 h = __float2bfloat16(f);
    return *reinterpret_cast<u16*>(&h);
}
__device__ inline bf16x8 cvt8(float4 lo, float4 hi) {
    bf16x8 r;
    r[0] = (short)f2bf(lo.x); r[1] = (short)f2bf(lo.y);
    r[2] = (short)f2bf(lo.z); r[3] = (short)f2bf(lo.w);
    r[4] = (short)f2bf(hi.x); r[5] = (short)f2bf(hi.y);
    r[6] = (short)f2bf(hi.z); r[7] = (short)f2bf(hi.w);
    return r;
}
// async global(16B/lane) -> LDS (wave-uniform base + lane*16)
__device__ inline void glds16(const u16* g, u16* l) {
    __builtin_amdgcn_global_load_lds(
        (const __attribute__((address_space(1))) u32*)g,
        (__attribute__((address_space(3))) u32*)l, 16, 0, 0);
}

// edge_index may arrive as int64 (reference dtype) or int32 (harness policy).
__global__ void k_detect(const unsigned int* e32, int* flag) {
    if (threadIdx.x == 0) {
        int is64 = 1;
        for (int i = 0; i < 64; ++i)
            if (e32[2 * i + 1] != 0u) { is64 = 0; break; }
        *flag = is64;
    }
}

__device__ inline int eidx(const void* p, int is64, int i) {
    if (is64) return (int)((const long long*)p)[i];
    return ((const int*)p)[i];
}

// Convert v3: LDS-staged coarse bucketing (8 buckets), no per-edge atomics.
__global__ __launch_bounds__(256) void k_convert_bucket3(
    const void* edges, const int* flag,
    unsigned int* __restrict__ buckets, int* __restrict__ bcur,
    int2* __restrict__ ovf, int* __restrict__ ovfn) {
    __shared__ unsigned int lbuf[8][CB_CAP];   // 8 KB
    __shared__ int lcnt[8];
    __shared__ int lbase[8];
    int t = threadIdx.x;
    if (t < 8) lcnt[t] = 0;
    __syncthreads();
    int e0 = blockIdx.x * CB_EDGES;
    int is64 = *flag;
#pragma unroll
    for (int j = 0; j < CB_EDGES / 256; ++j) {
        int i = e0 + j * 256 + t;              // coalesced per j-step
        int r = eidx(edges, is64, i);
        int c = eidx(edges, is64, N_EDGES + i);
        int b = c / 12500;
        int coff = c - b * 12500;
        unsigned int pack = ((unsigned)coff << 17) | (unsigned)r;
        int pos = atomicAdd(&lcnt[b], 1);
        if (pos < CB_CAP) {
            lbuf[b][pos] = pack;
        } else {
            int op = atomicAdd(ovfn, 1);
            if (op < OVCAP) ovf[op] = make_int2(c, r);
        }
    }
    __syncthreads();
    int sub = blockIdx.x & (NSUB - 1);
    if (t < 8) {
        int n = min(lcnt[t], CB_CAP);
        lbase[t] = atomicAdd(&bcur[t * NSUB + sub], n);
    }
    __syncthreads();
#pragma unroll
    for (int bb = 0; bb < 8; ++bb) {
        int n = min(lcnt[bb], CB_CAP);
        int base = lbase[bb];
        size_t segoff = ((size_t)(bb * NSUB + sub)) * SEGCAP;
        for (int i = t; i < n; i += 256) {
            int pos = base + i;
            unsigned int pk = lbuf[bb][i];
            if (pos < SEGCAP) {
                buckets[segoff + pos] = pk;
            } else {
                int c = bb * 12500 + (int)(pk >> 17);
                int r = (int)(pk & 0x1FFFFu);
                int op = atomicAdd(ovfn, 1);
                if (op < OVCAP) ovf[op] = make_int2(c, r);
            }
        }
    }
}

// Sub-partition: segment (b,sub) -> 128 node-window sub-buckets (WN=98 nodes).
__global__ __launch_bounds__(256) void k_subpart(
    const unsigned int* __restrict__ buckets, const int* __restrict__ bcur,
    unsigned int* __restrict__ subbuck, int* __restrict__ scur,
    int2* __restrict__ ovf, int* __restrict__ ovfn) {
    __shared__ unsigned int sbin[NWIN][SB_CAP];   // 24.6 KB
    __shared__ int scnt[NWIN];
    __shared__ int sbase[NWIN];
    int t = threadIdx.x;
    int b = blockIdx.x & 7;
    int sub = blockIdx.x >> 3;
    int idx = b * NSUB + sub;
    if (t < NWIN) scnt[t] = 0;
    __syncthreads();
    int n = min(bcur[idx], SEGCAP);
    const unsigned int* bk = buckets + (size_t)idx * SEGCAP;
    for (int e = t; e < n; e += 256) {
        unsigned int pk = bk[e];
        int j = (int)(pk >> 17) / WN;             // window 0..127
        int p = atomicAdd(&scnt[j], 1);
        if (p < SB_CAP) {
            sbin[j][p] = pk;
        } else {
            int c = b * 12500 + (int)(pk >> 17);
            int r = (int)(pk & 0x1FFFFu);
            int op = atomicAdd(ovfn, 1);
            if (op < OVCAP) ovf[op] = make_int2(c, r);
        }
    }
    __syncthreads();
    if (t < NWIN) {
        int cnt = min(scnt[t], SB_CAP);
        sbase[t] = atomicAdd(&scur[b * NWIN + t], cnt);
    }
    __syncthreads();
    for (int i = t; i < NWIN * SB_CAP; i += 256) {
        int j = i / SB_CAP, s = i % SB_CAP;
        if (s < min(scnt[j], SB_CAP)) {
            int pos = sbase[j] + s;
            unsigned int pk = sbin[j][s];
            if (pos < SUBCAP) {
                subbuck[((size_t)(b * NWIN + j)) * SUBCAP + pos] = pk;
            } else {
                int c = b * 12500 + (int)(pk >> 17);
                int r = (int)(pk & 0x1FFFFu);
                int op = atomicAdd(ovfn, 1);
                if (op < OVCAP) ovf[op] = make_int2(c, r);
            }
        }
    }
}

// Degree histogram v2: one block per node-window (1024 blocks).
__global__ __launch_bounds__(256) void k_deghist2(const unsigned int* __restrict__ subbuck,
                                                  const int* __restrict__ scur,
                                                  int* __restrict__ deg) {
    __shared__ int h[WN];
    int t = threadIdx.x;
    int b = blockIdx.x & 7;
    int j = blockIdx.x >> 3;                  // 0..NWIN-1
    int base_node = b * 12500 + j * WN;
    int nn = min(WN, 12500 - j * WN);
    if (t < WN) h[t] = 0;
    __syncthreads();
    int idx = b * NWIN + j;
    int n = min(scur[idx], SUBCAP);
    const unsigned int* sb = subbuck + (size_t)idx * SUBCAP;
    for (int e = t; e < n; e += 256)
        atomicAdd(&h[(int)(sb[e] >> 17) - j * WN], 1);
    __syncthreads();
    if (t < nn) deg[base_node + t] = h[t];    // plain store (exclusive window)
}

// Overflow deg contribution (normally zero entries) — runs AFTER k_deghist2
__global__ void k_deg_ovf(const int2* __restrict__ ovf, const int* __restrict__ ovfn,
                          int* deg) {
    int n = min(*ovfn, OVCAP);
    for (int i = blockIdx.x * 256 + threadIdx.x; i < n; i += gridDim.x * 256)
        atomicAdd(&deg[ovf[i].x], 1);
}

// ---- two-level scan: local scan -> scan of block sums -> apply ----
__global__ __launch_bounds__(SCAN_BS) void k_scan_part(const int* __restrict__ deg,
                                                       int* __restrict__ ptr,
                                                       int* __restrict__ bsum) {
    __shared__ int lds[SCAN_BS];
    int t = threadIdx.x;
    int idx = blockIdx.x * SCAN_BS + t;
    int s = (idx < N_NODES) ? deg[idx] : 0;
    lds[t] = s;
    __syncthreads();
#pragma unroll
    for (int off = 1; off < SCAN_BS; off <<= 1) {
        int v = (t >= off) ? lds[t - off] : 0;
        __syncthreads();
        lds[t] += v;
        __syncthreads();
    }
    if (idx < N_NODES) ptr[idx] = lds[t] - s;     // exclusive local
    if (t == SCAN_BS - 1) bsum[blockIdx.x] = lds[t];
}

__global__ __launch_bounds__(256) void k_scan_bsum(const int* __restrict__ bsum,
                                                   int* __restrict__ boff,
                                                   int* __restrict__ ptr) {
    __shared__ int lds[256];
    int t = threadIdx.x;
    int s = (t < SCAN_NB) ? bsum[t] : 0;
    lds[t] = s;
    __syncthreads();
#pragma unroll
    for (int off = 1; off < 256; off <<= 1) {
        int v = (t >= off) ? lds[t - off] : 0;
        __syncthreads();
        lds[t] += v;
        __syncthreads();
    }
    if (t < SCAN_NB) boff[t] = lds[t] - s;        // exclusive
    if (t == 255) ptr[N_NODES] = lds[t];          // total (== N_EDGES)
}

__global__ __launch_bounds__(SCAN_BS) void k_scan_apply(const int* __restrict__ deg,
                                                        const int* __restrict__ boff,
                                                        int* __restrict__ ptr,
                                                        int* __restrict__ cursor,
                                                        float* __restrict__ dinv) {
    int idx = blockIdx.x * SCAN_BS + threadIdx.x;
    if (idx >= N_NODES) return;
    int p = ptr[idx] + boff[blockIdx.x];
    ptr[idx] = p;
    cursor[idx] = p;
    dinv[idx] = rsqrtf((float)(deg[idx] + 1));    // +1 self loop
}

// Fill v6: one block EXCLUSIVELY owns node window (b,j) -> cursors in LDS.
__global__ __launch_bounds__(256) void k_fill6(const unsigned int* __restrict__ subbuck,
                                               const int* __restrict__ scur,
                                               const int* __restrict__ ptr,
                                               int* __restrict__ cursor,
                                               int* __restrict__ csr_src) {
    __shared__ int lcur[WN];
    int t = threadIdx.x;
    int b = blockIdx.x & 7;
    int j = blockIdx.x >> 3;                  // 0..NWIN-1
    int base_node = b * 12500 + j * WN;
    int nn = min(WN, 12500 - j * WN);         // last window is short
    if (t < nn) lcur[t] = ptr[base_node + t];
    __syncthreads();
    int idx = b * NWIN + j;
    int n = min(scur[idx], SUBCAP);
    const unsigned int* sb = subbuck + (size_t)idx * SUBCAP;
    for (int e = t; e < n; e += 256) {
        unsigned int pk = sb[e];
        int local = (int)(pk >> 17) - j * WN; // in [0, nn)
        int r = (int)(pk & 0x1FFFFu);
        int pos = atomicAdd(&lcur[local], 1); // LDS atomic — cheap
        csr_src[pos] = r;
    }
    __syncthreads();
    if (t < nn) cursor[base_node + t] = lcur[t];
}

// Overflow cleanup (normally zero entries) — runs AFTER k_fill6
__global__ void k_fill_ovf(const int2* __restrict__ ovf, const int* __restrict__ ovfn,
                           int* cursor, int* __restrict__ csr_src) {
    int n = min(*ovfn, OVCAP);
    for (int i = blockIdx.x * 256 + threadIdx.x; i < n; i += gridDim.x * 256) {
        int2 e = ovf[i];
        csr_src[atomicAdd(&cursor[e.x], 1)] = e.y;
    }
}

// W1 [500,256] f32 -> W1s bf16 [ks=16][n=256][kk=32] with slot-XOR swizzle.
__global__ void k_wconv1(const float* W1, u16* W1s) {
    int idx = blockIdx.x * 256 + threadIdx.x;
    if (idx >= 16 * 256 * 32) return;
    int ks = idx / (256 * 32);
    int rem = idx % (256 * 32);
    int n = rem / 32, kk = rem % 32;
    int k = ks * 32 + kk;
    float v = (k < 500) ? W1[k * 256 + n] : 0.0f;
    int slot = kk >> 3, kl = kk & 7;
    int sslot = slot ^ ((n >> 1) & 3);
    W1s[ks * 8192 + n * 32 + sslot * 8 + kl] = f2bf(v);
}

// W2 [256,64] f32 -> W2s bf16 swizzled [ks=8][n=64][kk=32] (unswizzled slots)
__global__ void k_wconv2(const float* W2, u16* W2s) {
    int idx = blockIdx.x * 256 + threadIdx.x;
    if (idx >= 8 * 64 * 32) return;
    int ks = idx / (64 * 32);
    int rem = idx % (64 * 32);
    int n = rem / 32, kk = rem % 32;
    int k = ks * 32 + kk;
    W2s[idx] = f2bf(W2[k * 64 + n]);
}

// Fused MLP v7: 64x256 tile, 4 waves/block (256 thr), BK=32, 16 steps,
// simple double-buffered K-loop (R15 structure — R16's asm pipeline reverted:
// it spilled and regressed). Smaller block => LDS exactly 40960B and regs
// <=128/wave => FOUR independent blocks/CU at different K-phases — block-level
// latency hiding (the m114 mechanism) instead of the failed intra-block
// pipelining. Wave w owns rows w*16..+15, all 256 cols (acc = 16 frags).
#define MLP3_ROWS 64
#define HSTR 264    // u16 stride for H rows
#define H2STR 72    // u16 stride for pack buffer

__global__ __launch_bounds__(256, 4) void k_mlp3(
    const float* __restrict__ x, const u16* __restrict__ W1s,
    const float* __restrict__ b1, const u16* __restrict__ W2s,
    const float* __restrict__ b2, const float* __restrict__ dinv,
    u16* __restrict__ h_bf, u16* __restrict__ zs0) {

    __shared__ u16 smem[20480];   // 40960 B: [A 2x2048 | B 2x8192]; H reuses
    u16* Abuf = smem;             // 2 * 2048 u16 (64 rows x 32 k)
    u16* Bbuf = smem + 4096;      // 2 * 8192 u16

    int t = threadIdx.x;
    int lane = t & 63, w = t >> 6;            // w = 0..3
    int cl = lane & 15, hi = lane >> 4;
    int m0 = blockIdx.x * MLP3_ROWS;

    // A staging: thread t stages row sr (0..63), k-slot skq (8 k's)
    int sr = t >> 2, skq = t & 3;
    int srow = min(m0 + sr, N_NODES - 1);
    const size_t XMAX = (size_t)N_NODES * 500 - 4;  // last valid float4 start
    size_t sbase = (size_t)srow * 500 + skq * 8;
    int sAoff = sr * 32 + ((skq ^ ((sr >> 1) & 3)) << 3);  // swizzled u16 offset

    f32x4 acc[16];
    f32x4 zero = {0.f, 0.f, 0.f, 0.f};
#pragma unroll
    for (int i = 0; i < 16; ++i) acc[i] = zero;

    float4 pa, pb;

    // ---- prologue: stage ks=0 into buffer 0 ----
    {
        size_t f = sbase;
        size_t a0 = f > XMAX ? XMAX : f;
        size_t a1 = (f + 4) > XMAX ? XMAX : (f + 4);
        pa = *(const float4*)(x + a0);
        pb = *(const float4*)(x + a1);
#pragma unroll
        for (int q = 0; q < 4; ++q)
            glds16(W1s + (w * 4 + q) * 512 + lane * 8, Bbuf + (w * 4 + q) * 512);
        bf16x8 av = cvt8(pa, pb);
        *(bf16x8*)&Abuf[sAoff] = av;
    }
    __syncthreads();

    for (int ks = 0; ks < 16; ++ks) {
        int cur = ks & 1, nxt = cur ^ 1;
        if (ks < 15) {
            // issue next-step loads EARLY (T14): A->regs, B->LDS(next)
            size_t f = sbase + (size_t)(ks + 1) * 32;
            size_t a0 = f > XMAX ? XMAX : f;
            size_t a1 = (f + 4) > XMAX ? XMAX : (f + 4);
            pa = *(const float4*)(x + a0);
            pb = *(const float4*)(x + a1);
            const u16* bsrc = W1s + (ks + 1) * 8192;
#pragma unroll
            for (int q = 0; q < 4; ++q)
                glds16(bsrc + (w * 4 + q) * 512 + lane * 8,
                       Bbuf + nxt * 8192 + (w * 4 + q) * 512);
        }
        // ---- compute on cur: pure ds_read + MFMA ----
        const u16* Ab = Abuf + cur * 2048;
        const u16* Bb = Bbuf + cur * 8192;
        int row = w * 16 + cl;
        bf16x8 af = *(const bf16x8*)&Ab[row * 32 + ((hi ^ ((row >> 1) & 3)) << 3)];
#pragma unroll
        for (int nt = 0; nt < 16; ++nt) {
            int n = nt * 16 + cl;
            bf16x8 bv = *(const bf16x8*)&Bb[n * 32 + ((hi ^ ((n >> 1) & 3)) << 3)];
            acc[nt] = __builtin_amdgcn_mfma_f32_16x16x32_bf16(af, bv, acc[nt], 0, 0, 0);
        }
        if (ks < 15) {
            // write A(next) LATE (vmcnt wait lands here, after the MFMAs)
            bf16x8 av = cvt8(pa, pb);
            *(bf16x8*)&Abuf[nxt * 2048 + sAoff] = av;
        }
        __syncthreads();
    }

    // ---- epilogue 1: +b1, relu -> H (wave-private 16 rows; no barrier) ----
    u16* H = smem;
#pragma unroll
    for (int nt = 0; nt < 16; ++nt) {
        int col = nt * 16 + cl;
        float bb = b1[col];
#pragma unroll
        for (int r = 0; r < 4; ++r) {
            int row = w * 16 + hi * 4 + r;
            H[row * HSTR + col] = f2bf(fmaxf(acc[nt][r] + bb, 0.0f));
        }
    }

    // ---- GEMM2: wave w handles its own rows w*16..+15; W2s from global ----
    f32x4 acc2[4];
#pragma unroll
    for (int i = 0; i < 4; ++i) acc2[i] = zero;
    int rA0 = w * 16 + cl;
#pragma unroll
    for (int ks2 = 0; ks2 < 8; ++ks2) {
        bf16x8 afv = *(const bf16x8*)&H[rA0 * HSTR + ks2 * 32 + 8 * hi];
#pragma unroll
        for (int nt = 0; nt < 4; ++nt) {
            bf16x8 bv = *(const bf16x8*)(W2s + (ks2 * 64 + nt * 16 + cl) * 32 + 8 * hi);
            acc2[nt] = __builtin_amdgcn_mfma_f32_16x16x32_bf16(afv, bv, acc2[nt], 0, 0, 0);
        }
    }
    __syncthreads();   // H dead; reuse as pack buffer

    // ---- epilogue 2: +b2 -> H2 ----
    u16* H2 = smem;
    {
        int rl0 = w * 16 + hi * 4;
#pragma unroll
        for (int nt = 0; nt < 4; ++nt) {
            int col = nt * 16 + cl;
            float bb = b2[col];
#pragma unroll
            for (int r = 0; r < 4; ++r)
                H2[(rl0 + r) * H2STR + col] = f2bf(acc2[nt][r] + bb);
        }
    }
    __syncthreads();

    // ---- pack & store: thread t handles a quarter row (16 u16 = 32B) ----
    {
        int rl = t >> 2, q = t & 3;
        int grow = m0 + rl;
        if (grow < N_NODES) {
            float dv = dinv[grow];
            const u32x4* src = (const u32x4*)&H2[rl * H2STR + q * 16];
            u32x4 hq[2] = {src[0], src[1]};
            u32x4 zq[2];
#pragma unroll
            for (int i = 0; i < 2; ++i) {
#pragma unroll
                for (int jj = 0; jj < 4; ++jj) {
                    unsigned int hw = hq[i][jj];
                    float lo = dv * bf2f_lo(hw);
                    float hi2 = dv * bf2f_hi(hw);
                    zq[i][jj] = (unsigned)f2bf(lo) | ((unsigned)f2bf(hi2) << 16);
                }
            }
            u32x4* hd = (u32x4*)(h_bf + (size_t)grow * 64 + q * 16);
            u32x4* zd = (u32x4*)(zs0 + (size_t)grow * 64 + q * 16);
            hd[0] = hq[0]; hd[1] = hq[1];
            zd[0] = zq[0]; zd[1] = zq[1];
        }
    }
}

// Propagation v3: one wave per node, dwordx4 gathers of 8 edges.
__global__ __launch_bounds__(256) void k_prop3(
    const u16* __restrict__ zs_in, const u16* __restrict__ h_bf,
    const float* __restrict__ dinv, const int* __restrict__ ptr,
    const int* __restrict__ csr_src, u16* __restrict__ zs_out,
    float* __restrict__ out, int last) {

    int lane = threadIdx.x & 63;
    int g = lane >> 3;   // edge slot 0..7
    int c = lane & 7;    // channels 8c..8c+7
    int v = blockIdx.x * 4 + (threadIdx.x >> 6);
    if (v >= N_NODES) return;
    int s0 = ptr[v], s1 = ptr[v + 1];

    float a0 = 0.f, a1 = 0.f, a2 = 0.f, a3 = 0.f;
    float a4 = 0.f, a5 = 0.f, a6 = 0.f, a7 = 0.f;
    float b0 = 0.f, b1 = 0.f, b2 = 0.f, b3 = 0.f;
    float b4 = 0.f, b5 = 0.f, b6 = 0.f, b7 = 0.f;

    for (int base = s0; base < s1; base += 64) {
        int nwin = min(64, s1 - base);
        int ei = base + lane;
        int sv = (ei < s1) ? csr_src[ei] : v;   // fallback: safe address
        int j = 0;
        for (; j + 16 <= nwin; j += 16) {
            int u0 = __shfl(sv, j + g, 64);
            int u1 = __shfl(sv, j + 8 + g, 64);
            u32x4 q0 = *(const u32x4*)(zs_in + (size_t)u0 * 64 + c * 8);
            u32x4 q1 = *(const u32x4*)(zs_in + (size_t)u1 * 64 + c * 8);
            a0 += bf2f_lo(q0.x); a1 += bf2f_hi(q0.x);
            a2 += bf2f_lo(q0.y); a3 += bf2f_hi(q0.y);
            a4 += bf2f_lo(q0.z); a5 += bf2f_hi(q0.z);
            a6 += bf2f_lo(q0.w); a7 += bf2f_hi(q0.w);
            b0 += bf2f_lo(q1.x); b1 += bf2f_hi(q1.x);
            b2 += bf2f_lo(q1.y); b3 += bf2f_hi(q1.y);
            b4 += bf2f_lo(q1.z); b5 += bf2f_hi(q1.z);
            b6 += bf2f_lo(q1.w); b7 += bf2f_hi(q1.w);
        }
        for (; j < nwin; j += 8) {
            int idx = j + g;
            int u = __shfl(sv, idx, 64);  // idx<=63; invalid lanes hold v (safe)
            u32x4 q = *(const u32x4*)(zs_in + (size_t)u * 64 + c * 8);
            if (idx < nwin) {
                a0 += bf2f_lo(q.x); a1 += bf2f_hi(q.x);
                a2 += bf2f_lo(q.y); a3 += bf2f_hi(q.y);
                a4 += bf2f_lo(q.z); a5 += bf2f_hi(q.z);
                a6 += bf2f_lo(q.w); a7 += bf2f_hi(q.w);
            }
        }
    }
    a0 += b0; a1 += b1; a2 += b2; a3 += b3;
    a4 += b4; a5 += b5; a6 += b6; a7 += b7;
#pragma unroll
    for (int off = 8; off <= 32; off <<= 1) {
        a0 += __shfl_xor(a0, off, 64); a1 += __shfl_xor(a1, off, 64);
        a2 += __shfl_xor(a2, off, 64); a3 += __shfl_xor(a3, off, 64);
        a4 += __shfl_xor(a4, off, 64); a5 += __shfl_xor(a5, off, 64);
        a6 += __shfl_xor(a6, off, 64); a7 += __shfl_xor(a7, off, 64);
    }

    float dv = dinv[v];
    u32x4 qs = *(const u32x4*)(zs_in + (size_t)v * 64 + c * 8);
    u32x4 qh = *(const u32x4*)(h_bf + (size_t)v * 64 + c * 8);
    float z0 = (1.0f - ALPHA) * dv * (a0 + bf2f_lo(qs.x)) + ALPHA * bf2f_lo(qh.x);
    float z1 = (1.0f - ALPHA) * dv * (a1 + bf2f_hi(qs.x)) + ALPHA * bf2f_hi(qh.x);
    float z2 = (1.0f - ALPHA) * dv * (a2 + bf2f_lo(qs.y)) + ALPHA * bf2f_lo(qh.y);
    float z3 = (1.0f - ALPHA) * dv * (a3 + bf2f_hi(qs.y)) + ALPHA * bf2f_hi(qh.y);
    float z4 = (1.0f - ALPHA) * dv * (a4 + bf2f_lo(qs.z)) + ALPHA * bf2f_lo(qh.z);
    float z5 = (1.0f - ALPHA) * dv * (a5 + bf2f_hi(qs.z)) + ALPHA * bf2f_hi(qh.z);
    float z6 = (1.0f - ALPHA) * dv * (a6 + bf2f_lo(qs.w)) + ALPHA * bf2f_lo(qh.w);
    float z7 = (1.0f - ALPHA) * dv * (a7 + bf2f_hi(qs.w)) + ALPHA * bf2f_hi(qh.w);

    if (!last) {
        if (g == 0) {
            u32x4 o;
            o.x = (unsigned)f2bf(dv * z0) | ((unsigned)f2bf(dv * z1) << 16);
            o.y = (unsigned)f2bf(dv * z2) | ((unsigned)f2bf(dv * z3) << 16);
            o.z = (unsigned)f2bf(dv * z4) | ((unsigned)f2bf(dv * z5) << 16);
            o.w = (unsigned)f2bf(dv * z6) | ((unsigned)f2bf(dv * z7) << 16);
            *(u32x4*)(zs_out + (size_t)v * 64 + c * 8) = o;
        }
    } else {
        float m = fmaxf(fmaxf(fmaxf(z0, z1), fmaxf(z2, z3)),
                        fmaxf(fmaxf(z4, z5), fmaxf(z6, z7)));
#pragma unroll
        for (int off = 1; off <= 4; off <<= 1) m = fmaxf(m, __shfl_xor(m, off, 64));
        float p = expf(z0 - m) + expf(z1 - m) + expf(z2 - m) + expf(z3 - m)
                + expf(z4 - m) + expf(z5 - m) + expf(z6 - m) + expf(z7 - m);
#pragma unroll
        for (int off = 1; off <= 4; off <<= 1) p += __shfl_xor(p, off, 64);
        float ls = logf(p);
        if (g == 0) {
            f32x4 o1 = {z0 - m - ls, z1 - m - ls, z2 - m - ls, z3 - m - ls};
            f32x4 o2 = {z4 - m - ls, z5 - m - ls, z6 - m - ls, z7 - m - ls};
            *(f32x4*)(out + (size_t)v * 64 + c * 8) = o1;
            *(f32x4*)(out + (size_t)v * 64 + c * 8 + 4) = o2;
        }
    }
}

extern "C" void kernel_launch(void* const* d_in, const int* in_sizes, int n_in,
                              void* d_out, int out_size, void* d_ws, size_t ws_size,
                              hipStream_t stream) {
    const float* x  = (const float*)d_in[0];
    const void* edges = d_in[1];
    const float* W1 = (const float*)d_in[2];
    const float* b1 = (const float*)d_in[3];
    const float* W2 = (const float*)d_in[4];
    const float* b2 = (const float*)d_in[5];
    float* out = (float*)d_out;

    char* ws = (char*)d_ws;
    size_t off = 0;
    auto alloc = [&](size_t bytes) -> void* {
        void* p = ws + off;
        off = (off + bytes + 255) & ~(size_t)255;
        return p;
    };
    int*   flag    = (int*)alloc(4);
    int*   deg     = (int*)alloc((size_t)N_NODES * 4);
    float* dinv    = (float*)alloc((size_t)N_NODES * 4);
    int*   ptr     = (int*)alloc((size_t)(N_NODES + 1) * 4);
    int*   cursor  = (int*)alloc((size_t)N_NODES * 4);
    int*   bsum    = (int*)alloc((size_t)SCAN_NB * 4);
    int*   boff    = (int*)alloc((size_t)SCAN_NB * 4);
    int*   csr_src = (int*)alloc((size_t)N_EDGES * 4);
    u16*   W1s     = (u16*)alloc((size_t)16 * 256 * 32 * 2);
    u16*   W2s     = (u16*)alloc((size_t)8 * 64 * 32 * 2);
    u16*   h_bf    = (u16*)alloc((size_t)N_NODES * 64 * 2);
    u16*   zsA     = (u16*)alloc((size_t)N_NODES * 64 * 2);
    u32*   buckets = (u32*)alloc((size_t)8 * NSUB * SEGCAP * 4);   // 16.8MB
    u32*   subbuck = (u32*)alloc((size_t)8 * NWIN * SUBCAP * 4);   // 16.8MB; zsB aliases
    int*   bctl    = (int*)alloc((size_t)(8 * NSUB + 8 * NWIN + 16) * 4);
    int2*  ovf     = (int2*)alloc((size_t)OVCAP * 8);
    u16*   zsB     = (u16*)subbuck;  // subbuck dead after fill6; 16.8MB >= 12.8MB

    int* bcur = bctl;                      // [8*NSUB]
    int* scur = bctl + 8 * NSUB;           // [8*NWIN]
    int* ovfn = bctl + 8 * NSUB + 8 * NWIN;

    hipMemsetAsync(deg, 0, (size_t)N_NODES * 4, stream);
    hipMemsetAsync(bctl, 0, (size_t)(8 * NSUB + 8 * NWIN + 16) * 4, stream);
    k_detect<<<1, 64, 0, stream>>>((const unsigned int*)edges, flag);
    k_convert_bucket3<<<N_EDGES / CB_EDGES, 256, 0, stream>>>(edges, flag,
                                                              buckets, bcur, ovf, ovfn);
    k_subpart<<<8 * NSUB, 256, 0, stream>>>(buckets, bcur, subbuck, scur, ovf, ovfn);
    k_deghist2<<<8 * NWIN, 256, 0, stream>>>(subbuck, scur, deg);
    k_deg_ovf<<<32, 256, 0, stream>>>(ovf, ovfn, deg);
    k_scan_part<<<SCAN_NB, SCAN_BS, 0, stream>>>(deg, ptr, bsum);
    k_scan_bsum<<<1, 256, 0, stream>>>(bsum, boff, ptr);
    k_scan_apply<<<SCAN_NB, SCAN_BS, 0, stream>>>(deg, boff, ptr, cursor, dinv);
    k_fill6<<<8 * NWIN, 256, 0, stream>>>(subbuck, scur, ptr, cursor, csr_src);
    k_fill_ovf<<<64, 256, 0, stream>>>(ovf, ovfn, cursor, csr_src);
    k_wconv1<<<(16 * 256 * 32 + 255) / 256, 256, 0, stream>>>(W1, W1s);
    k_wconv2<<<(8 * 64 * 32 + 255) / 256, 256, 0, stream>>>(W2, W2s);
    k_mlp3<<<(N_NODES + MLP3_ROWS - 1) / MLP3_ROWS, 256, 0, stream>>>(x, W1s, b1, W2s, b2,
                                                                      dinv, h_bf, zsA);

    const u16* zin = zsA;
    u16* zout = zsB;
    for (int k = 0; k < KITER; ++k) {
        int last = (k == KITER - 1) ? 1 : 0;
        k_prop3<<<(N_NODES + 3) / 4, 256, 0, stream>>>(zin, h_bf, dinv, ptr, csr_src,
                                                       zout, out, last);
        u16* t = zout;
        zout = (u16*)zin;
        zin = t;
    }
}